// Round 6
// baseline (175.399 us; speedup 1.0000x reference)
//
#include <hip/hip_runtime.h>
#include <hip/hip_fp16.h>

#define N_NODES 100000
#define N_RELS  2000
#define D       128
#define DEG     16

// ws layout: [ relws: 2000*float2 (padded to 16384B) | feat16 | rel16 ]
#define RELWS_BYTES  16384
#define FEAT16_BYTES ((size_t)N_NODES * D * 2)   // 25,600,000
#define REL16_BYTES  ((size_t)N_RELS * D * 2)    // 512,000
#define WS_NEED      (RELWS_BYTES + FEAT16_BYTES + REL16_BYTES)

static __device__ __forceinline__ __half2 bc_h2(unsigned int u) {
  return __builtin_bit_cast(__half2, u);
}
static __device__ __forceinline__ int bc_i(float f) {
  return __builtin_bit_cast(int, f);
}
static __device__ __forceinline__ float bc_f(int i) {
  return __builtin_bit_cast(float, i);
}

// DPP ctrl must be a literal constant at the builtin call -> template param.
template <int CTRL>
static __device__ __forceinline__ float dpp_add(float v) {
  return v + bc_f(__builtin_amdgcn_update_dpp(0, bc_i(v), CTRL, 0xF, 0xF, false));
}

// ---------- kernel 1: per-relation precompute + fp16 convert (fused) ----------
__global__ __launch_bounds__(256) void rel_pre_kernel(
    const float* __restrict__ rel_emb,
    const float* __restrict__ attn,
    float2* __restrict__ relws,
    unsigned int* __restrict__ rel16u) {
  const int wave = threadIdx.x >> 6;
  const int lane = threadIdx.x & 63;
  const int r = blockIdx.x * 4 + wave;
  float2 ev = *(const float2*)(rel_emb + (size_t)r * D + lane * 2);
  float2 av = *(const float2*)(attn + lane * 2);
  rel16u[r * 64 + lane] =
      __builtin_bit_cast(unsigned int, __builtin_amdgcn_cvt_pkrtz(ev.x, ev.y));
  float ss = ev.x * ev.x + ev.y * ev.y;
  float dt = ev.x * av.x + ev.y * av.y;
#pragma unroll
  for (int off = 32; off >= 1; off >>= 1) {
    ss += __shfl_xor(ss, off, 64);
    dt += __shfl_xor(dt, off, 64);
  }
  if (lane == 0) {
    float inv = rsqrtf(fmaxf(ss, 1e-12f));
    relws[r] = make_float2(inv, expf(dt));
  }
}

// ---------- kernel 2: fp32 -> fp16 feature compression ----------
__global__ __launch_bounds__(256) void cvt_f32_f16_kernel(
    const float* __restrict__ src, uint2* __restrict__ dst) {
  const int i = blockIdx.x * 256 + threadIdx.x;  // float4 index
  float4 v = ((const float4*)src)[i];
  uint2 o;
  o.x = __builtin_bit_cast(unsigned int, __builtin_amdgcn_cvt_pkrtz(v.x, v.y));
  o.y = __builtin_bit_cast(unsigned int, __builtin_amdgcn_cvt_pkrtz(v.z, v.w));
  dst[i] = o;
}

// ---------- kernel 3: main. 16 lanes/node, 4 nodes/wave, no LDS ----------
// lane (g,s): owns edge s of node g AND dim-chunk s (8 halves) of node g's
// output. Three phases so no cross-lane op sits inside the gather chain:
//   A: gather of/ef, per-lane pd partial, acc1 += att*of      (pure load+FMA)
//   B: 16 batched row-reductions of pd (DPP row_shr + ds_swizzle bcast)
//   C: reload ef (L2-hot), acc2 += (cf*pd)*ef                 (pure load+FMA)
__global__ __launch_bounds__(256) void gat16_kernel(
    const int* __restrict__ triples,
    const unsigned short* __restrict__ feat16,
    const unsigned short* __restrict__ rel16,
    const float2* __restrict__ relws,
    float* __restrict__ out) {
  const int tid  = threadIdx.x;
  const int s    = tid & 15;
  const int g    = (tid >> 4) & 3;
  const int wave = tid >> 6;
  const int node = blockIdx.x * 16 + wave * 4 + g;

  // This lane's edge (node g, edge s).
  const int* t = triples + (size_t)node * (DEG * 3);
  const int tr = t[3 * s + 1];
  const int to = t[3 * s + 2];
  const float2 ia = relws[tr];  // (inv_norm, att)
  const float att = ia.y;
  const float cf  = 2.f * att * ia.x;

  // den over the 16 edges of this node.
  float den = att;
  den += __shfl_xor(den, 1);
  den += __shfl_xor(den, 2);
  den += __shfl_xor(den, 4);
  den += __shfl_xor(den, 8);
  const float rden = 1.f / den;

  // Broadcast every edge's record into registers (hoisted, independent).
  const int pidx = (to << 11) | tr;  // obj:17b | rel:11b
  const int pattcf =
      __builtin_bit_cast(int, __builtin_amdgcn_cvt_pkrtz(att, cf));
  const int srcBase = tid & 48;  // wave-local first lane of my 16-lane group
  int pb[DEG], ab[DEG];
#pragma unroll
  for (int i = 0; i < DEG; ++i) {
    pb[i] = __shfl(pidx, srcBase + i, 64);
    ab[i] = __shfl(pattcf, srcBase + i, 64);
  }

  // ---- Phase A ----
  float pd[DEG];
  __half2 acc1[4];
#pragma unroll
  for (int j = 0; j < 4; ++j) acc1[j] = __float2half2_rn(0.f);

#pragma unroll
  for (int i = 0; i < DEG; ++i) {
    const uint4 of = *(const uint4*)(feat16 + (size_t)(pb[i] >> 11) * D + s * 8);
    const uint4 ef = *(const uint4*)(rel16 + (size_t)(pb[i] & 2047) * D + s * 8);
    const __half2 o0 = bc_h2(of.x), o1 = bc_h2(of.y), o2 = bc_h2(of.z), o3 = bc_h2(of.w);
    const __half2 e0 = bc_h2(ef.x), e1 = bc_h2(ef.y), e2 = bc_h2(ef.z), e3 = bc_h2(ef.w);

    __half2 pp = __hmul2(o0, e0);
    pp = __hfma2(o1, e1, pp);
    pp = __hfma2(o2, e2, pp);
    pp = __hfma2(o3, e3, pp);
    pd[i] = __low2float(pp) + __high2float(pp);

    const __half2 att2 = __half2half2(__low2half(bc_h2((unsigned int)ab[i])));
    acc1[0] = __hfma2(att2, o0, acc1[0]);
    acc1[1] = __hfma2(att2, o1, acc1[1]);
    acc1[2] = __hfma2(att2, o2, acc1[2]);
    acc1[3] = __hfma2(att2, o3, acc1[3]);
  }

  // ---- Phase B: 16 batched 16-lane reductions (VALU DPP), then bcast ----
#pragma unroll
  for (int i = 0; i < DEG; ++i) pd[i] = dpp_add<0x111>(pd[i]);  // row_shr:1
#pragma unroll
  for (int i = 0; i < DEG; ++i) pd[i] = dpp_add<0x112>(pd[i]);  // row_shr:2
#pragma unroll
  for (int i = 0; i < DEG; ++i) pd[i] = dpp_add<0x114>(pd[i]);  // row_shr:4
#pragma unroll
  for (int i = 0; i < DEG; ++i) pd[i] = dpp_add<0x118>(pd[i]);  // row_shr:8
#pragma unroll
  for (int i = 0; i < DEG; ++i) {
    // bcast lane15 within each 16-lane group (and=0x10, or=0xF)
    pd[i] = bc_f(__builtin_amdgcn_ds_swizzle(bc_i(pd[i]), 0x1F0));
  }

  // ---- Phase C: reload ef rows (L2-hot) and apply reflection term ----
  __half2 acc2[4];
#pragma unroll
  for (int j = 0; j < 4; ++j) acc2[j] = __float2half2_rn(0.f);

#pragma unroll
  for (int i = 0; i < DEG; ++i) {
    const uint4 ef = *(const uint4*)(rel16 + (size_t)(pb[i] & 2047) * D + s * 8);
    const float c = __high2float(bc_h2((unsigned int)ab[i])) * pd[i];
    const __half2 c2 = __float2half2_rn(c);
    acc2[0] = __hfma2(c2, bc_h2(ef.x), acc2[0]);
    acc2[1] = __hfma2(c2, bc_h2(ef.y), acc2[1]);
    acc2[2] = __hfma2(c2, bc_h2(ef.z), acc2[2]);
    acc2[3] = __hfma2(c2, bc_h2(ef.w), acc2[3]);
  }

  // out[d] = (acc1 - acc2) / den for this lane's 8 dims
  float* op = out + (size_t)node * D + s * 8;
  float4 r0, r1;
  {
    float2 a0 = __half22float2(acc1[0]), b0 = __half22float2(acc2[0]);
    float2 a1 = __half22float2(acc1[1]), b1 = __half22float2(acc2[1]);
    r0.x = (a0.x - b0.x) * rden; r0.y = (a0.y - b0.y) * rden;
    r0.z = (a1.x - b1.x) * rden; r0.w = (a1.y - b1.y) * rden;
    float2 a2 = __half22float2(acc1[2]), b2 = __half22float2(acc2[2]);
    float2 a3 = __half22float2(acc1[3]), b3 = __half22float2(acc2[3]);
    r1.x = (a2.x - b2.x) * rden; r1.y = (a2.y - b2.y) * rden;
    r1.z = (a3.x - b3.x) * rden; r1.w = (a3.y - b3.y) * rden;
  }
  *(float4*)op = r0;
  *(float4*)(op + 4) = r1;
}

// ---------- fallback (fp32 path) if ws is too small ----------
__global__ __launch_bounds__(256) void gat_kernel(
    const int* __restrict__ triples,
    const float* __restrict__ features,
    const float* __restrict__ rel_emb,
    const float2* __restrict__ relws,
    float* __restrict__ out) {
  const int wave = threadIdx.x >> 6;
  const int lane = threadIdx.x & 63;
  const int node = blockIdx.x * 4 + wave;
  const int* t = triples + (size_t)node * DEG * 3;
  int tv = (lane < DEG * 3) ? t[lane] : 0;
  float2 acc = make_float2(0.f, 0.f);
  float den = 0.f;
#pragma unroll
  for (int i = 0; i < DEG; ++i) {
    const int rel = __builtin_amdgcn_readfirstlane(__shfl(tv, 3 * i + 1, 64));
    const int obj = __builtin_amdgcn_readfirstlane(__shfl(tv, 3 * i + 2, 64));
    float2 ia = relws[rel];
    float2 ov = *(const float2*)(features + (size_t)obj * D + lane * 2);
    float2 ev = *(const float2*)(rel_emb + (size_t)rel * D + lane * 2);
    float pd = ov.x * ev.x + ov.y * ev.y;
#pragma unroll
    for (int off = 32; off >= 1; off >>= 1) pd += __shfl_xor(pd, off, 64);
    const float c = 2.f * pd * ia.x;
    const float att = ia.y;
    acc.x += att * (ov.x - c * ev.x);
    acc.y += att * (ov.y - c * ev.y);
    den += att;
  }
  const float r = 1.f / den;
  *(float2*)(out + (size_t)node * D + lane * 2) =
      make_float2(acc.x * r, acc.y * r);
}

extern "C" void kernel_launch(void* const* d_in, const int* in_sizes, int n_in,
                              void* d_out, int out_size, void* d_ws, size_t ws_size,
                              hipStream_t stream) {
  const int*   triples  = (const int*)d_in[0];
  const float* features = (const float*)d_in[1];
  const float* rel_emb  = (const float*)d_in[2];
  const float* attn     = (const float*)d_in[3];
  float*       out      = (float*)d_out;

  float2* relws = (float2*)d_ws;

  if (ws_size >= WS_NEED) {
    unsigned short* feat16 = (unsigned short*)((char*)d_ws + RELWS_BYTES);
    unsigned int*   rel16u = (unsigned int*)((char*)d_ws + RELWS_BYTES + FEAT16_BYTES);
    rel_pre_kernel<<<N_RELS / 4, 256, 0, stream>>>(rel_emb, attn, relws, rel16u);
    cvt_f32_f16_kernel<<<(N_NODES * D / 4) / 256, 256, 0, stream>>>(
        features, (uint2*)feat16);
    gat16_kernel<<<N_NODES / 16, 256, 0, stream>>>(
        triples, feat16, (const unsigned short*)rel16u, relws, out);
  } else {
    rel_pre_kernel<<<N_RELS / 4, 256, 0, stream>>>(rel_emb, attn, relws,
                                                   (unsigned int*)d_ws);
    gat_kernel<<<N_NODES / 4, 256, 0, stream>>>(
        triples, features, rel_emb, relws, out);
  }
}